// Round 2
// baseline (626.029 us; speedup 1.0000x reference)
//
#include <hip/hip_runtime.h>
#include <math.h>

// Pipeline (dtype of float inputs auto-detected: bf16 vs fp32; internal fp64/fp32/bf16):
//  0. detect     : 1 wave inspects pentachora u16 exponent fields -> flag (1=bf16 inputs, 0=fp32)
//  1. penta_sums : [32000,5,512] -> 15 fp64 sums per vocab (10 pair dist_sq, 5 centroid dist_sq)
//  2. coords     : fp64 Cayley-Menger det + stats + cantor loop -> ci[v] in [0,255] (exact int coord*256)
//  3. ctok       : gather ci[token_ids]
//  4. routes     : integer-distance histogram top-64, tie-break lowest index (= lax.top_k stable)
//  5. gemm qkv   : bf16 MFMA 16x16x32, 64x64 tile -> bf16 qkv[4096,1536]
//  6. attn       : wave per (b,q), 8 heads; gather bf16 k/v rows by routes; fp32 softmax -> bf16
//  7. gemm out   : bf16 MFMA -> d_out (dtype per flag)

typedef unsigned short u16;
typedef short short8 __attribute__((ext_vector_type(8)));
typedef u16 u16x8 __attribute__((ext_vector_type(8)));
typedef float floatx4 __attribute__((ext_vector_type(4)));

#define NVOCAB 32000
#define NSEQ 2048

__device__ inline float b2f(u16 u){
  union{unsigned int i; float f;} x; x.i = ((unsigned int)u)<<16; return x.f;
}
__device__ inline u16 f2b(float f){
  union{float f; unsigned int u;} x; x.f = f;
  unsigned int u = x.u;
  u += 0x7fffu + ((u >> 16) & 1u);   // RNE
  return (u16)(u >> 16);
}
__device__ inline double shfl_xor_d(double v, int m){
  union{double d; int i[2];} x; x.d = v;
  x.i[0] = __shfl_xor(x.i[0], m, 64);
  x.i[1] = __shfl_xor(x.i[1], m, 64);
  return x.d;
}

// ---------------- Stage 0: input dtype detection ----------------
// bf16 Gaussian data: every even-index u16 is a bf16 with exponent in ~[107,129].
// fp32 data: even-index u16s are low mantissa bits (uniform) -> P(all 64 in [96,144]) ~ 1e-46.
__global__ void detect_kernel(const u16* __restrict__ p, int* __restrict__ flag){
  int lane = threadIdx.x;
  u16 u = p[lane*2];
  int e = (u >> 7) & 0xff;
  bool pass = (e >= 96 && e <= 144);
  unsigned long long m = __ballot(pass);
  if (lane == 0) *flag = (m == ~0ull) ? 1 : 0;
}

// ---------------- Stage 1: per-vocab pair/centroid sums (fp64), wave per vocab ----------------
__global__ __launch_bounds__(256) void penta_sums_kernel(const void* __restrict__ penta,
                                                         const int* __restrict__ flagp,
                                                         double* __restrict__ sums){
  int f = *flagp;
  int w = blockIdx.x*4 + (threadIdx.x>>6);   // vocab index, 4 waves/block
  int lane = threadIdx.x & 63;
  float pf[5][8];
  if (f){   // bf16 inputs
    const u16* base = (const u16*)penta + (size_t)w*2560 + lane*8;
    #pragma unroll
    for (int i=0;i<5;i++){
      u16x8 u = *(const u16x8*)(base + i*512);
      #pragma unroll
      for (int j=0;j<8;j++) pf[i][j] = b2f(u[j]);
    }
  } else {  // fp32 inputs
    const float* base = (const float*)penta + (size_t)w*2560 + lane*8;
    #pragma unroll
    for (int i=0;i<5;i++){
      float4 f0 = *(const float4*)(base + i*512);
      float4 f1 = *(const float4*)(base + i*512 + 4);
      pf[i][0]=f0.x; pf[i][1]=f0.y; pf[i][2]=f0.z; pf[i][3]=f0.w;
      pf[i][4]=f1.x; pf[i][5]=f1.y; pf[i][6]=f1.z; pf[i][7]=f1.w;
    }
  }
  double acc[15];
  #pragma unroll
  for (int k=0;k<15;k++) acc[k]=0.0;
  #pragma unroll
  for (int j=0;j<8;j++){
    double p[5];
    #pragma unroll
    for (int i=0;i<5;i++) p[i] = (double)pf[i][j];
    double mean = (p[0]+p[1]+p[2]+p[3]+p[4])*0.2;
    int idx=0;
    #pragma unroll
    for (int a=0;a<5;a++)
      #pragma unroll
      for (int b=a+1;b<5;b++){ double d=p[a]-p[b]; acc[idx++] += d*d; }
    #pragma unroll
    for (int i=0;i<5;i++){ double d=p[i]-mean; acc[10+i] += d*d; }
  }
  #pragma unroll
  for (int k=0;k<15;k++){
    double s = acc[k];
    for (int off=32; off; off>>=1) s += shfl_xor_d(s, off);
    acc[k]=s;
  }
  if (lane==0){
    double* o = sums + (size_t)w*15;
    #pragma unroll
    for (int k=0;k<15;k++) o[k]=acc[k];
  }
}

// ---------------- Stage 2: fp64 det + stats + cantor, one thread per vocab ----------------
__global__ __launch_bounds__(256) void coords_kernel(const double* __restrict__ sums,
                                                     int* __restrict__ ci){
  int v = blockIdx.x*256 + threadIdx.x;
  if (v >= NVOCAB) return;
  const double* s = sums + (size_t)v*15;
  double ds[10], cd2[5];
  #pragma unroll
  for (int k=0;k<10;k++) ds[k]=s[k];
  #pragma unroll
  for (int k=0;k<5;k++) cd2[k]=s[10+k];
  // Cayley-Menger 6x6
  double M[6][6];
  M[0][0]=0.0;
  #pragma unroll
  for (int j=1;j<6;j++){ M[0][j]=1.0; M[j][0]=1.0; }
  {
    int idx=0;
    for (int a=0;a<5;a++){
      M[1+a][1+a]=0.0;
      for (int b=a+1;b<5;b++){ M[1+a][1+b]=ds[idx]; M[1+b][1+a]=ds[idx]; idx++; }
    }
  }
  double det=1.0;
  for (int c=0;c<6;c++){
    int piv=c; double mx=fabs(M[c][c]);
    for (int r=c+1;r<6;r++){ double a=fabs(M[r][c]); if (a>mx){mx=a;piv=r;} }
    if (piv!=c){
      for (int cc=0;cc<6;cc++){ double t=M[c][cc]; M[c][cc]=M[piv][cc]; M[piv][cc]=t; }
      det=-det;
    }
    double pv = M[c][c];
    det *= pv;
    if (pv != 0.0){
      for (int r=c+1;r<6;r++){
        double fq = M[r][c]/pv;
        for (int cc=c+1;cc<6;cc++) M[r][cc] -= fq*M[c][cc];
      }
    }
  }
  double volume = sqrt(fmax(-det/9216.0, 0.0));
  double vn = 1.0/(1.0+exp(-10.0*volume));
  double me=0.0, e[10];
  #pragma unroll
  for (int k=0;k<10;k++){ e[k]=sqrt(ds[k]); me+=e[k]; }
  me *= 0.1;
  double var=0.0;
  #pragma unroll
  for (int k=0;k<10;k++){ double d=e[k]-me; var+=d*d; }
  double se = sqrt(var/9.0);                    // ddof=1
  double er = 1.0/(1.0+exp(-(se/(me+1e-6))));
  double mc=0.0, cd[5];
  #pragma unroll
  for (int k=0;k<5;k++){ cd[k]=sqrt(cd2[k]); mc+=cd[k]; }
  mc *= 0.2;
  double v2=0.0;
  #pragma unroll
  for (int k=0;k<5;k++){ double d=cd[k]-mc; v2+=d*d; }
  double sp = sqrt(v2/4.0);                     // ddof=1
  double sn = 1.0/(1.0+exp(-sp));
  const double EPSd = 1e-6;
  double x = 0.4*vn + 0.3*er + 0.3*sn;
  x = fmin(fmax(x, EPSd), 1.0-EPSd);
  double bump = (vn+er+sn)*0.01;
  double cv=0.0, factor=0.5;
  #pragma unroll
  for (int it=0; it<8; it++){
    double xs = x*3.0;
    double frac = xs - floor(xs);
    if (xs >= 2.0) cv += factor;
    x = fmin(fmax(frac + bump, EPSd), 1.0-EPSd);
    factor *= 0.5;
  }
  cv = fmin(fmax(cv,0.0),1.0);
  ci[v] = (int)(cv*256.0 + 0.5);                // exact multiple of 1/256 -> exact int
}

// ---------------- Stage 3: gather coords for tokens ----------------
__global__ __launch_bounds__(256) void ctok_kernel(const int* __restrict__ ci,
                                                   const int* __restrict__ tok,
                                                   int* __restrict__ ctok){
  int i = blockIdx.x*256 + threadIdx.x;
  if (i < NSEQ) ctok[i] = ci[tok[i]];
}

// ---------------- Stage 4: top-64 neighbors by integer coord distance ----------------
__global__ __launch_bounds__(256) void routes_kernel(const int* __restrict__ ctok,
                                                     int* __restrict__ routes){
  __shared__ int cs[NSEQ];
  __shared__ int hist[256];
  __shared__ int cnts[256];
  __shared__ int params[3];   // T, need, out-counter
  int tid = threadIdx.x;
  int q = blockIdx.x;
  for (int j=tid; j<NSEQ; j+=256) cs[j] = ctok[j];
  hist[tid] = 0;
  __syncthreads();
  int cq = cs[q];
  int base = tid*8;
  int dloc[8];
  #pragma unroll
  for (int i=0;i<8;i++){
    int d = cs[base+i] - cq; d = d<0 ? -d : d;
    dloc[i] = d;
    atomicAdd(&hist[d], 1);
  }
  __syncthreads();
  if (tid==0){
    int cum=0, T=255, need=64;
    for (int d=0; d<256; d++){
      int h = hist[d];
      if (cum + h >= 64){ T=d; need=64-cum; break; }
      cum += h;
    }
    params[0]=T; params[1]=need; params[2]=0;
  }
  __syncthreads();
  int T=params[0], need=params[1];
  int ceq=0;
  #pragma unroll
  for (int i=0;i<8;i++) ceq += (dloc[i]==T) ? 1 : 0;
  cnts[tid]=ceq;
  __syncthreads();
  if (tid==0){
    int run=0;
    for (int t=0;t<256;t++){ int c=cnts[t]; cnts[t]=run; run+=c; }
  }
  __syncthreads();
  int rank = cnts[tid];
  int* rq = routes + q*64;
  #pragma unroll
  for (int i=0;i<8;i++){
    int d = dloc[i];
    bool sel = false;
    if (d < T) sel = true;
    else if (d == T){ sel = (rank < need); rank++; }
    if (sel){
      int pos = atomicAdd(&params[2], 1);
      rq[pos] = base + i;   // set semantics: order within the 64 doesn't matter for softmax
    }
  }
}

// ---------------- Stages 5/7: bf16 MFMA GEMM, 64x64 tile, BK=32 ----------------
// A_FOLLOW: 1 -> A dtype follows flag (bf16/fp32 input); 0 -> A is always bf16 (our buffer)
// C_FOLLOW: 1 -> C dtype follows flag (d_out);           0 -> C is always bf16 (our buffer)
template<int A_FOLLOW, int C_FOLLOW>
__global__ __launch_bounds__(256) void gemm64(const void* __restrict__ Ain,
    const void* __restrict__ W, const void* __restrict__ bias, void* __restrict__ Cout,
    const int* __restrict__ flagp, int M, int N, int K)
{
  int f = *flagp;                       // 1 = bf16 inputs
  bool a_f32 = A_FOLLOW ? (f==0) : false;
  bool w_f32 = (f==0);
  bool c_bf16 = C_FOLLOW ? (f==1) : true;
  __shared__ short Al[64][40];   // +8 pad
  __shared__ short Bl[64][40];   // transposed: Bl[n][k]
  int tid = threadIdx.x;
  int m0 = blockIdx.y<<6, n0 = blockIdx.x<<6;
  int wv = tid>>6, lane = tid&63, lr = lane&15, lq = lane>>4;
  floatx4 acc[4];
  #pragma unroll
  for (int t=0;t<4;t++) acc[t] = (floatx4){0.f,0.f,0.f,0.f};
  int arow = tid>>2, acg = (tid&3)<<3;
  int bkr = tid>>3, bng = (tid&7)<<3;
  for (int k0=0;k0<K;k0+=32){
    __syncthreads();
    if (a_f32){
      const float* Af = (const float*)Ain + (size_t)(m0+arow)*K + k0 + acg;
      float4 f0 = *(const float4*)Af;
      float4 f1 = *(const float4*)(Af+4);
      short8 t;
      t[0]=(short)f2b(f0.x); t[1]=(short)f2b(f0.y); t[2]=(short)f2b(f0.z); t[3]=(short)f2b(f0.w);
      t[4]=(short)f2b(f1.x); t[5]=(short)f2b(f1.y); t[6]=(short)f2b(f1.z); t[7]=(short)f2b(f1.w);
      *(short8*)&Al[arow][acg] = t;
    } else {
      const u16* Au = (const u16*)Ain + (size_t)(m0+arow)*K + k0 + acg;
      *(short8*)&Al[arow][acg] = *(const short8*)Au;
    }
    if (w_f32){
      const float* Wp = (const float*)W + (size_t)(k0+bkr)*N + n0 + bng;
      float4 w0 = *(const float4*)Wp;
      float4 w1 = *(const float4*)(Wp+4);
      Bl[bng+0][bkr]=(short)f2b(w0.x); Bl[bng+1][bkr]=(short)f2b(w0.y);
      Bl[bng+2][bkr]=(short)f2b(w0.z); Bl[bng+3][bkr]=(short)f2b(w0.w);
      Bl[bng+4][bkr]=(short)f2b(w1.x); Bl[bng+5][bkr]=(short)f2b(w1.y);
      Bl[bng+6][bkr]=(short)f2b(w1.z); Bl[bng+7][bkr]=(short)f2b(w1.w);
    } else {
      const u16* Wp = (const u16*)W + (size_t)(k0+bkr)*N + n0 + bng;
      u16x8 wvec = *(const u16x8*)Wp;
      #pragma unroll
      for (int i=0;i<8;i++) Bl[bng+i][bkr] = (short)wvec[i];
    }
    __syncthreads();
    short8 af = *(const short8*)&Al[(wv<<4)+lr][lq<<3];
    #pragma unroll
    for (int t4=0;t4<4;t4++){
      short8 bfv = *(const short8*)&Bl[(t4<<4)+lr][lq<<3];
      acc[t4] = __builtin_amdgcn_mfma_f32_16x16x32_bf16(af, bfv, acc[t4], 0, 0, 0);
    }
  }
  // C/D: row = lq*4 + r, col = lane&15
  #pragma unroll
  for (int t4=0;t4<4;t4++){
    #pragma unroll
    for (int r=0;r<4;r++){
      int m = m0 + (wv<<4) + (lq<<2) + r;
      int n = n0 + (t4<<4) + lr;
      float bv = w_f32 ? ((const float*)bias)[n] : b2f(((const u16*)bias)[n]);
      float val = acc[t4][r] + bv;
      if (c_bf16) ((u16*)Cout)[(size_t)m*N + n] = f2b(val);
      else        ((float*)Cout)[(size_t)m*N + n] = val;
    }
  }
}

// ---------------- Stage 6: gather attention, 1 wave per (b,q), 8 heads, bf16 qkv ----------------
__global__ __launch_bounds__(64) void attn_kernel(const u16* __restrict__ qkv,
                                                  const int* __restrict__ routes,
                                                  u16* __restrict__ outa){
  __shared__ __align__(16) float qbuf[64];
  __shared__ float abuf[64];
  __shared__ int rbuf[64];
  int lane = threadIdx.x;
  int bq = blockIdx.x;            // = b*2048 + q
  int b = bq >> 11;
  int q = bq & 2047;
  rbuf[lane] = routes[(q<<6) + lane];
  __syncthreads();
  int myroute = rbuf[lane];
  const u16* kbase = qkv + (size_t)((b<<11) + myroute)*1536 + 512;
  for (int h=0; h<8; h++){
    qbuf[lane] = b2f(qkv[(size_t)bq*1536 + (h<<6) + lane]);
    __syncthreads();
    // scores: lane j streams its own k row, q via LDS broadcast
    const u16* kr = kbase + (h<<6);
    float s = 0.f;
    #pragma unroll
    for (int i=0;i<8;i++){
      u16x8 kv8 = *(const u16x8*)(kr + 8*i);
      #pragma unroll
      for (int j=0;j<8;j++) s = fmaf(b2f(kv8[j]), qbuf[8*i+j], s);
    }
    s *= 0.125f;   // 1/sqrt(64)
    float mx = s;
    for (int off=32; off; off>>=1) mx = fmaxf(mx, __shfl_xor(mx, off, 64));
    float e = expf(s - mx);
    float sm = e;
    for (int off=32; off; off>>=1) sm += __shfl_xor(sm, off, 64);
    abuf[lane] = e / sm;
    __syncthreads();
    // output: lane = d, coalesced v rows
    float acc = 0.f;
    for (int j=0;j<64;j++){
      int rj = rbuf[j];
      acc = fmaf(abuf[j], b2f(qkv[(size_t)((b<<11)+rj)*1536 + 1024 + (h<<6) + lane]), acc);
    }
    outa[(size_t)bq*512 + (h<<6) + lane] = f2b(acc);
    __syncthreads();
  }
}

extern "C" void kernel_launch(void* const* d_in, const int* in_sizes, int n_in,
                              void* d_out, int out_size, void* d_ws, size_t ws_size,
                              hipStream_t stream) {
  const void* penta = d_in[0];   // [32000,5,512]
  const void* x     = d_in[1];   // [2,2048,512]
  const int*  tok   = (const int*)d_in[2];   // [2048]
  const void* Wqkv  = d_in[3];   // [512,1536]
  const void* bqkv  = d_in[4];   // [1536]
  const void* Wout  = d_in[5];   // [512,512]
  const void* bout  = d_in[6];   // [512]

  char* ws = (char*)d_ws;
  int*    ci     = (int*)   (ws + 0);          // 128000 B
  int*    flag   = (int*)   (ws + 128000);     // 4 B
  int*    ctok   = (int*)   (ws + 131072);     // 8192 B
  int*    routes = (int*)   (ws + 139264);     // 524288 B   (end 663552)
  double* sums   = (double*)(ws + 663552);     // 3840000 B  (transient; overlaps qkv)
  u16*    qkv    = (u16*)   (ws + 663552);     // 12582912 B (end 13246464)
  u16*    attn   = (u16*)   (ws + 13246464);   // 4194304 B  (end 17440768 ~ 16.6 MB)

  detect_kernel<<<dim3(1), dim3(64), 0, stream>>>((const u16*)penta, flag);
  penta_sums_kernel<<<dim3(8000), dim3(256), 0, stream>>>(penta, flag, sums);
  coords_kernel<<<dim3(125), dim3(256), 0, stream>>>(sums, ci);
  ctok_kernel<<<dim3(8), dim3(256), 0, stream>>>(ci, tok, ctok);
  routes_kernel<<<dim3(2048), dim3(256), 0, stream>>>(ctok, routes);
  gemm64<1,0><<<dim3(24, 64), dim3(256), 0, stream>>>(x, Wqkv, bqkv, (void*)qkv, flag, 4096, 1536, 512);
  attn_kernel<<<dim3(4096), dim3(64), 0, stream>>>(qkv, routes, attn);
  gemm64<0,1><<<dim3(8, 64), dim3(256), 0, stream>>>((const void*)attn, Wout, bout, d_out, flag, 4096, 512, 512);
}